// Round 5
// baseline (60.127 us; speedup 1.0000x reference)
//
#include <hip/hip_runtime.h>

#define PTPB  256    // prep threads per block
#define TPB   256    // nn threads per block (4 waves)
#define QPT   8      // query points per thread (registers)
#define SPLIT 64     // database slices per direction
#define RTPB  256    // reduce threads per block
#define QPR   4      // queries per reduce thread (float4)

// ---------------------------------------------------------------------------
// Prep: pack DB points as (-2x, -2y, -2z, |t|^2) float4 so the nn candidate
// is a pure 3-fma chain; fold label poisoning (invalid pred points -> coords 0,
// tn = 1e10, matching the reference BIG mask). dbpack rows: [0,B) = target DB
// (for dir 0), [B,2B) = pred DB (for dir 1). Also zeroes the reduce counter.
// ---------------------------------------------------------------------------
__global__ void __launch_bounds__(PTPB) prep_kernel(
    const float* __restrict__ pred,
    const float* __restrict__ target,
    const int*   __restrict__ label,
    float4* __restrict__ dbpack,
    unsigned int* __restrict__ counter,
    int B, int N, int M, int stride)
{
    int i = blockIdx.x * blockDim.x + threadIdx.x;
    if (i == 0) *counter = 0u;

    int totalT = B * M;
    int totalP = B * N;
    if (i < totalT) {                        // dir 0 DB: target, all valid
        int b = i / M, j = i - b * M;
        const float* sp = target + (size_t)i * 3;
        float x = sp[0], y = sp[1], z = sp[2];
        float tn = fmaf(x, x, fmaf(y, y, z * z));
        dbpack[(size_t)b * stride + j] = make_float4(-2.f * x, -2.f * y, -2.f * z, tn);
    } else if (i < totalT + totalP) {        // dir 1 DB: pred, label-masked
        int k = i - totalT;
        int b = k / N, j = k - b * N;
        const float* sp = pred + (size_t)k * 3;
        float x = sp[0], y = sp[1], z = sp[2];
        float tn = fmaf(x, x, fmaf(y, y, z * z));
        if (label[k] != 1) { x = 0.f; y = 0.f; z = 0.f; tn = 1.0e10f; }
        dbpack[((size_t)B + b) * stride + j] = make_float4(-2.f * x, -2.f * y, -2.f * z, tn);
    }
}

// ---------------------------------------------------------------------------
// nn: directed nearest-neighbor min, both directions in one launch.
// Queries in VGPRs (QPT per thread); DB points read via WAVE-UNIFORM indexing
// of dbpack -> compiler emits s_load (scalar pipe), so the hot loop is pure
// VALU: v = fma(px,sx, fma(py,sy, fma(pz,sz, tn))), min3 amortized.
// No LDS, no __syncthreads. Each (tile,split) block writes to a private
// minsplit slot: no atomics, bit-deterministic.
// grid = (B * natmax, SPLIT, 2).
// ---------------------------------------------------------------------------
__global__ void __launch_bounds__(TPB) nn_kernel(
    const float* __restrict__ pred,
    const float* __restrict__ target,
    const float4* __restrict__ dbpack,
    float* __restrict__ minsplit,     // [2][B][SPLIT][stride]
    int B, int N, int M, int natmax, int stride)
{
    const int dir = blockIdx.z;
    const float* __restrict__ A = dir ? target : pred;
    const int NA = dir ? M : N;
    const int NB = dir ? N : M;

    const int natiles = (NA + TPB * QPT - 1) / (TPB * QPT);
    const int b  = blockIdx.x / natmax;
    const int at = blockIdx.x - b * natmax;
    if (at >= natiles) return;

    const size_t abase = (size_t)b * NA;

    float px[QPT], py[QPT], pz[QPT], pn[QPT], best[QPT];
#pragma unroll
    for (int q = 0; q < QPT; ++q) {
        int a = at * (TPB * QPT) + q * TPB + threadIdx.x;
        int idx = (a < NA) ? a : 0;
        const float* sp = A + (abase + idx) * 3;
        px[q] = sp[0];
        py[q] = sp[1];
        pz[q] = sp[2];
        pn[q] = fmaf(px[q], px[q], fmaf(py[q], py[q], pz[q] * pz[q]));
        best[q] = 3.0e38f;
    }

    const int slen = (NB + SPLIT - 1) / SPLIT;
    const int sbeg = blockIdx.y * slen;
    const int send = min(sbeg + slen, NB);
    const float4* __restrict__ db = dbpack + ((size_t)dir * B + b) * stride;

    int j = sbeg;
#pragma unroll 4
    for (; j + 2 <= send; j += 2) {
        float4 t0 = db[j];        // uniform address -> s_load (scalar pipe)
        float4 t1 = db[j + 1];
#pragma unroll
        for (int q = 0; q < QPT; ++q) {
            float v0 = fmaf(px[q], t0.x, fmaf(py[q], t0.y, fmaf(pz[q], t0.z, t0.w)));
            float v1 = fmaf(px[q], t1.x, fmaf(py[q], t1.y, fmaf(pz[q], t1.z, t1.w)));
            best[q] = fminf(best[q], fminf(v0, v1));   // -> v_min3_f32
        }
    }
    if (j < send) {
        float4 t0 = db[j];
#pragma unroll
        for (int q = 0; q < QPT; ++q) {
            float v0 = fmaf(px[q], t0.x, fmaf(py[q], t0.y, fmaf(pz[q], t0.z, t0.w)));
            best[q] = fminf(best[q], v0);
        }
    }

    float* out = minsplit + (((size_t)dir * B + b) * SPLIT + blockIdx.y) * stride;
#pragma unroll
    for (int q = 0; q < QPT; ++q) {
        int a = at * (TPB * QPT) + q * TPB + threadIdx.x;
        if (a < NA) {
            out[a] = fmaxf(best[q] + pn[q], 0.0f);
        }
    }
}

// ---------------------------------------------------------------------------
// Reduce: per-query min over SPLIT slices (float4 loads), sqrt, masked sums,
// block reduce, last-block final combine (device-scope atomics only).
// ---------------------------------------------------------------------------
__device__ __forceinline__ float block_reduce_sum(float v, float* red) {
    int tid = threadIdx.x;
    red[tid] = v;
    __syncthreads();
    for (int s = RTPB / 2; s > 0; s >>= 1) {
        if (tid < s) red[tid] += red[tid + s];
        __syncthreads();
    }
    float r = red[0];
    __syncthreads();
    return r;
}

__global__ void __launch_bounds__(RTPB) reduce_kernel(
    const float* __restrict__ minsplit,
    const int* __restrict__ label,
    float* __restrict__ pS, float* __restrict__ pC,
    unsigned int* __restrict__ counter,
    float* __restrict__ out,
    int B, int N, int M, int tilesN, int tilesM, int stride, int nblocks)
{
    __shared__ float red[RTPB];
    const int r = blockIdx.x;

    int dir, b, t, NA;
    if (r < B * tilesN) { dir = 0; b = r / tilesN; t = r - b * tilesN; NA = N; }
    else { int r2 = r - B * tilesN; dir = 1; b = r2 / tilesM; t = r2 - b * tilesM; NA = M; }

    const float* base = minsplit + (((size_t)dir * B + b) * SPLIT) * stride;
    const int q0 = t * (RTPB * QPR) + threadIdx.x * QPR;

    float s = 0.0f, cc = 0.0f;
    if (q0 + QPR <= NA) {
        float4 mv = *reinterpret_cast<const float4*>(base + q0);
#pragma unroll 8
        for (int sp = 1; sp < SPLIT; ++sp) {
            float4 v = *reinterpret_cast<const float4*>(base + (size_t)sp * stride + q0);
            mv.x = fminf(mv.x, v.x);
            mv.y = fminf(mv.y, v.y);
            mv.z = fminf(mv.z, v.z);
            mv.w = fminf(mv.w, v.w);
        }
        if (dir == 0) {
            int4 lb = *reinterpret_cast<const int4*>(label + (size_t)b * N + q0);
            if (lb.x == 1) { s += sqrtf(mv.x); cc += 1.0f; }
            if (lb.y == 1) { s += sqrtf(mv.y); cc += 1.0f; }
            if (lb.z == 1) { s += sqrtf(mv.z); cc += 1.0f; }
            if (lb.w == 1) { s += sqrtf(mv.w); cc += 1.0f; }
        } else {
            s = sqrtf(mv.x) + sqrtf(mv.y) + sqrtf(mv.z) + sqrtf(mv.w);
        }
    } else {
        for (int k = 0; k < QPR; ++k) {
            int q = q0 + k;
            if (q < NA) {
                float m = base[q];
                for (int sp = 1; sp < SPLIT; ++sp) {
                    m = fminf(m, base[(size_t)sp * stride + q]);
                }
                if (dir == 0) {
                    if (label[(size_t)b * N + q] == 1) { s += sqrtf(m); cc += 1.0f; }
                } else {
                    s += sqrtf(m);
                }
            }
        }
    }

    s = block_reduce_sum(s, red);
    if (dir == 0) cc = block_reduce_sum(cc, red);

    if (threadIdx.x == 0) {
        atomicExch(&pS[r], s);                 // device-scope, XCD-coherent
        atomicExch(&pC[r], cc);
        __threadfence();
        unsigned int old = atomicAdd(counter, 1u);
        if (old == (unsigned int)(nblocks - 1)) {
            float acc = 0.0f;
            for (int bb = 0; bb < B; ++bb) {
                float S1 = 0.0f, C1 = 0.0f, S2 = 0.0f;
                for (int i = 0; i < tilesN; ++i) {
                    S1 += atomicAdd(&pS[bb * tilesN + i], 0.0f);
                    C1 += atomicAdd(&pC[bb * tilesN + i], 0.0f);
                }
                for (int i = 0; i < tilesM; ++i) {
                    S2 += atomicAdd(&pS[B * tilesN + bb * tilesM + i], 0.0f);
                }
                float m1 = S1 / fmaxf(C1, 1.0f);
                float m2 = S2 / (float)M;
                acc += 0.5f * (m1 + m2);
            }
            out[0] = acc / (float)B;   // * LOSS_WEIGHT (== 1.0)
        }
    }
}

// ---------------------------------------------------------------------------
extern "C" void kernel_launch(void* const* d_in, const int* in_sizes, int n_in,
                              void* d_out, int out_size, void* d_ws, size_t ws_size,
                              hipStream_t stream) {
    const float* pred   = (const float*)d_in[0];  // B*N*3 f32
    const float* target = (const float*)d_in[1];  // B*M*3 f32
    const int*   label  = (const int*)  d_in[2];  // B*N   i32

    const int B = in_sizes[3];                 // nums has shape (B,)
    const int N = in_sizes[2] / B;             // label is B*N
    const int M = in_sizes[1] / (3 * B);       // target is B*M*3

    const int stride = (N > M) ? N : M;

    // workspace layout (~8.6 MiB of the provided scratch)
    float4* dbpack = (float4*)d_ws;                               // 2*B*stride
    float* minsplit = (float*)(dbpack + (size_t)2 * B * stride);  // 2*B*SPLIT*stride
    const int tilesN = (N + RTPB * QPR - 1) / (RTPB * QPR);
    const int tilesM = (M + RTPB * QPR - 1) / (RTPB * QPR);
    const int nred = B * (tilesN + tilesM);
    float* pS = minsplit + (size_t)2 * B * SPLIT * stride;        // nred
    float* pC = pS + nred;                                        // nred
    unsigned int* counter = (unsigned int*)(pC + nred);

    const int nprep = B * (N + M);
    prep_kernel<<<(nprep + PTPB - 1) / PTPB, PTPB, 0, stream>>>(
        pred, target, label, dbpack, counter, B, N, M, stride);

    const int nat1 = (N + TPB * QPT - 1) / (TPB * QPT);
    const int nat2 = (M + TPB * QPT - 1) / (TPB * QPT);
    const int natmax = (nat1 > nat2) ? nat1 : nat2;
    dim3 g(B * natmax, SPLIT, 2);
    nn_kernel<<<g, TPB, 0, stream>>>(pred, target, dbpack, minsplit,
                                     B, N, M, natmax, stride);

    reduce_kernel<<<nred, RTPB, 0, stream>>>(minsplit, label, pS, pC, counter,
                                             (float*)d_out,
                                             B, N, M, tilesN, tilesM, stride, nred);
}

// Round 6
// 42.714 us; speedup vs baseline: 1.4077x; 1.4077x over previous
//
#include <hip/hip_runtime.h>

#define TPB   256    // nn threads per block (4 waves)
#define QPT   16     // query points per thread (registers)
#define SPLIT 128    // database slices per direction (4096/128 = 32 = one stage)
#define RTPB  256    // reduce threads per block
#define QPR   4      // queries per reduce thread (float4)
#define MAXPART 512  // max partials the fused final combine supports

// ---------------------------------------------------------------------------
// nn: directed nearest-neighbor min, both directions in one launch.
//   blockIdx.z = 0 : query = pred  (NA=N), DB = target (NB=M), all valid
//   blockIdx.z = 1 : query = target(NA=M), DB = pred   (NB=N), label-masked
// Staging packs each DB point as (-2x, -2y, -2z, |t|^2) (label poisoning
// folded in: invalid -> coords 0, tn = 1e10 == reference BIG). Candidate is a
// pure 3-fma chain: v = fma(px,sx, fma(py,sy, fma(pz,sz, tn))); min over v is
// min over d shifted by |p|^2 (added once per query at the end, clamped >=0).
// QPT=16 queries/thread: one LDS broadcast read feeds 16 fma-chains ->
// LDS traffic ~43% of VALU (was ~86% at QPT=8) -> VALU-bound.
// 4 blocks/CU, 4 waves/SIMD. Each (b,split) slice staged by exactly one
// block per direction; one barrier pair per block. No atomics, deterministic.
// Also zeroes the reduce kernel's completion counter.
// grid = (B * natmax, SPLIT, 2).
// ---------------------------------------------------------------------------
__global__ void __launch_bounds__(TPB) nn_kernel(
    const float* __restrict__ pred,
    const float* __restrict__ target,
    const int*   __restrict__ label,
    float* __restrict__ minsplit,     // [2][B][SPLIT][stride]
    unsigned int* __restrict__ counter,
    int B, int N, int M, int natmax, int stride)
{
    __shared__ float4 tile[TPB];

    if (blockIdx.x == 0 && blockIdx.y == 0 && blockIdx.z == 0 && threadIdx.x == 0) {
        *counter = 0u;   // consumed by reduce_kernel's last-block detection
    }

    const int dir = blockIdx.z;
    const float* __restrict__ A  = dir ? target : pred;
    const float* __restrict__ Bp = dir ? pred   : target;
    const int NA = dir ? M : N;
    const int NB = dir ? N : M;
    const int* __restrict__ labB = dir ? label : nullptr;

    const int natiles = (NA + TPB * QPT - 1) / (TPB * QPT);
    const int b  = blockIdx.x / natmax;
    const int at = blockIdx.x - b * natmax;
    if (at >= natiles) return;

    const size_t abase = (size_t)b * NA;

    float px[QPT], py[QPT], pz[QPT], pn[QPT], best[QPT];
#pragma unroll
    for (int q = 0; q < QPT; ++q) {
        int a = at * (TPB * QPT) + q * TPB + threadIdx.x;
        int idx = (a < NA) ? a : 0;
        const float* sp = A + (abase + idx) * 3;
        px[q] = sp[0];
        py[q] = sp[1];
        pz[q] = sp[2];
        pn[q] = fmaf(px[q], px[q], fmaf(py[q], py[q], pz[q] * pz[q]));
        best[q] = 3.0e38f;
    }

    const int slen = (NB + SPLIT - 1) / SPLIT;
    const int sbeg = blockIdx.y * slen;
    const int send = min(sbeg + slen, NB);
    const size_t bbase = (size_t)b * NB;

    for (int c = sbeg; c < send; c += TPB) {
        const int cnt = min(send - c, TPB);
        if (threadIdx.x < cnt) {
            int m = c + threadIdx.x;
            const float* sp = Bp + (bbase + m) * 3;
            float x = sp[0], y = sp[1], z = sp[2];
            float tn = fmaf(x, x, fmaf(y, y, z * z));
            if (labB != nullptr && labB[bbase + m] != 1) {   // invalid point
                x = 0.0f; y = 0.0f; z = 0.0f; tn = 1.0e10f;
            }
            tile[threadIdx.x] = make_float4(-2.f * x, -2.f * y, -2.f * z, tn);
        }
        __syncthreads();

        const int jeven = cnt & ~1;
#pragma unroll 2
        for (int j = 0; j < jeven; j += 2) {
            float4 t0 = tile[j];      // wave-uniform -> LDS broadcast
            float4 t1 = tile[j + 1];
#pragma unroll
            for (int q = 0; q < QPT; ++q) {
                float v0 = fmaf(px[q], t0.x, fmaf(py[q], t0.y, fmaf(pz[q], t0.z, t0.w)));
                float v1 = fmaf(px[q], t1.x, fmaf(py[q], t1.y, fmaf(pz[q], t1.z, t1.w)));
                best[q] = fminf(best[q], fminf(v0, v1));   // -> v_min3_f32
            }
        }
        if (cnt & 1) {
            float4 t0 = tile[cnt - 1];
#pragma unroll
            for (int q = 0; q < QPT; ++q) {
                float v0 = fmaf(px[q], t0.x, fmaf(py[q], t0.y, fmaf(pz[q], t0.z, t0.w)));
                best[q] = fminf(best[q], v0);
            }
        }
        __syncthreads();              // protect tile before next stage write
    }

    float* out = minsplit + (((size_t)dir * B + b) * SPLIT + blockIdx.y) * stride;
#pragma unroll
    for (int q = 0; q < QPT; ++q) {
        int a = at * (TPB * QPT) + q * TPB + threadIdx.x;
        if (a < NA) {
            out[a] = fmaxf(best[q] + pn[q], 0.0f);
        }
    }
}

// ---------------------------------------------------------------------------
// Reduce: per-query min over SPLIT slices (float4 loads), sqrt, masked sums,
// block reduce, then last-block final combine with PARALLEL partial loading
// (one device-scope atomic read per thread into LDS, not serial in thread 0).
// ---------------------------------------------------------------------------
__device__ __forceinline__ float block_reduce_sum(float v, float* red) {
    int tid = threadIdx.x;
    red[tid] = v;
    __syncthreads();
    for (int s = RTPB / 2; s > 0; s >>= 1) {
        if (tid < s) red[tid] += red[tid + s];
        __syncthreads();
    }
    float r = red[0];
    __syncthreads();
    return r;
}

__global__ void __launch_bounds__(RTPB) reduce_kernel(
    const float* __restrict__ minsplit,
    const int* __restrict__ label,
    float* __restrict__ pS, float* __restrict__ pC,
    unsigned int* __restrict__ counter,
    float* __restrict__ out,
    int B, int N, int M, int tilesN, int tilesM, int stride, int nblocks)
{
    __shared__ float red[RTPB];
    const int r = blockIdx.x;

    int dir, b, t, NA;
    if (r < B * tilesN) { dir = 0; b = r / tilesN; t = r - b * tilesN; NA = N; }
    else { int r2 = r - B * tilesN; dir = 1; b = r2 / tilesM; t = r2 - b * tilesM; NA = M; }

    const float* base = minsplit + (((size_t)dir * B + b) * SPLIT) * stride;
    const int q0 = t * (RTPB * QPR) + threadIdx.x * QPR;

    float s = 0.0f, cc = 0.0f;
    if (q0 + QPR <= NA) {
        float4 mv = *reinterpret_cast<const float4*>(base + q0);
#pragma unroll 8
        for (int sp = 1; sp < SPLIT; ++sp) {
            float4 v = *reinterpret_cast<const float4*>(base + (size_t)sp * stride + q0);
            mv.x = fminf(mv.x, v.x);
            mv.y = fminf(mv.y, v.y);
            mv.z = fminf(mv.z, v.z);
            mv.w = fminf(mv.w, v.w);
        }
        if (dir == 0) {
            int4 lb = *reinterpret_cast<const int4*>(label + (size_t)b * N + q0);
            if (lb.x == 1) { s += sqrtf(mv.x); cc += 1.0f; }
            if (lb.y == 1) { s += sqrtf(mv.y); cc += 1.0f; }
            if (lb.z == 1) { s += sqrtf(mv.z); cc += 1.0f; }
            if (lb.w == 1) { s += sqrtf(mv.w); cc += 1.0f; }
        } else {
            s = sqrtf(mv.x) + sqrtf(mv.y) + sqrtf(mv.z) + sqrtf(mv.w);
        }
    } else {
        for (int k = 0; k < QPR; ++k) {
            int q = q0 + k;
            if (q < NA) {
                float m = base[q];
                for (int sp = 1; sp < SPLIT; ++sp) {
                    m = fminf(m, base[(size_t)sp * stride + q]);
                }
                if (dir == 0) {
                    if (label[(size_t)b * N + q] == 1) { s += sqrtf(m); cc += 1.0f; }
                } else {
                    s += sqrtf(m);
                }
            }
        }
    }

    s = block_reduce_sum(s, red);
    if (dir == 0) cc = block_reduce_sum(cc, red);

    __shared__ unsigned int is_last;
    if (threadIdx.x == 0) {
        atomicExch(&pS[r], s);                 // device-scope, XCD-coherent
        atomicExch(&pC[r], (dir == 0) ? cc : 0.0f);
        __threadfence();
        unsigned int old = atomicAdd(counter, 1u);
        is_last = (old == (unsigned int)(nblocks - 1)) ? 1u : 0u;
    }
    __syncthreads();

    if (is_last) {
        __shared__ float sS[MAXPART], sC[MAXPART];
        for (int i = threadIdx.x; i < nblocks; i += RTPB) {
            sS[i] = atomicAdd(&pS[i], 0.0f);   // device-scope reads, parallel
            sC[i] = atomicAdd(&pC[i], 0.0f);
        }
        __syncthreads();
        if (threadIdx.x == 0) {
            float acc = 0.0f;
            for (int bb = 0; bb < B; ++bb) {
                float S1 = 0.0f, C1 = 0.0f, S2 = 0.0f;
                for (int i = 0; i < tilesN; ++i) {
                    S1 += sS[bb * tilesN + i];
                    C1 += sC[bb * tilesN + i];
                }
                for (int i = 0; i < tilesM; ++i) {
                    S2 += sS[B * tilesN + bb * tilesM + i];
                }
                float m1 = S1 / fmaxf(C1, 1.0f);
                float m2 = S2 / (float)M;
                acc += 0.5f * (m1 + m2);
            }
            out[0] = acc / (float)B;   // * LOSS_WEIGHT (== 1.0)
        }
    }
}

// ---------------------------------------------------------------------------
extern "C" void kernel_launch(void* const* d_in, const int* in_sizes, int n_in,
                              void* d_out, int out_size, void* d_ws, size_t ws_size,
                              hipStream_t stream) {
    const float* pred   = (const float*)d_in[0];  // B*N*3 f32
    const float* target = (const float*)d_in[1];  // B*M*3 f32
    const int*   label  = (const int*)  d_in[2];  // B*N   i32

    const int B = in_sizes[3];                 // nums has shape (B,)
    const int N = in_sizes[2] / B;             // label is B*N
    const int M = in_sizes[1] / (3 * B);       // target is B*M*3

    const int stride = (N > M) ? N : M;

    // workspace layout (~16.8 MiB of the provided scratch)
    float* minsplit = (float*)d_ws;                               // 2*B*SPLIT*stride
    const int tilesN = (N + RTPB * QPR - 1) / (RTPB * QPR);
    const int tilesM = (M + RTPB * QPR - 1) / (RTPB * QPR);
    const int nred = B * (tilesN + tilesM);
    float* pS = minsplit + (size_t)2 * B * SPLIT * stride;        // nred
    float* pC = pS + nred;                                        // nred
    unsigned int* counter = (unsigned int*)(pC + nred);

    const int nat1 = (N + TPB * QPT - 1) / (TPB * QPT);
    const int nat2 = (M + TPB * QPT - 1) / (TPB * QPT);
    const int natmax = (nat1 > nat2) ? nat1 : nat2;
    dim3 g(B * natmax, SPLIT, 2);
    nn_kernel<<<g, TPB, 0, stream>>>(pred, target, label, minsplit, counter,
                                     B, N, M, natmax, stride);

    reduce_kernel<<<nred, RTPB, 0, stream>>>(minsplit, label, pS, pC, counter,
                                             (float*)d_out,
                                             B, N, M, tilesN, tilesM, stride, nred);
}

// Round 7
// 36.372 us; speedup vs baseline: 1.6531x; 1.1744x over previous
//
#include <hip/hip_runtime.h>

#define TPB   256    // nn threads per block (4 waves)
#define QPT   16     // query points per thread (registers)
#define SPLIT 128    // database slices per direction (4096/128 = 32 = one stage)
#define RTPB  256    // reduce1 threads per block (64 queries x 4 slice-groups)
#define QCHUNK 64    // queries per reduce1 block

// ---------------------------------------------------------------------------
// nn: directed nearest-neighbor min, both directions in one launch.
//   blockIdx.z = 0 : query = pred  (NA=N), DB = target (NB=M), all valid
//   blockIdx.z = 1 : query = target(NA=M), DB = pred   (NB=N), label-masked
// Staging packs each DB point as (-2x, -2y, -2z, |t|^2) (label poisoning
// folded in: invalid -> coords 0, tn = 1e10 == reference BIG). Candidate is a
// pure 3-fma chain: v = fma(px,sx, fma(py,sy, fma(pz,sz, tn))); min over v is
// min over d shifted by |p|^2 (added once per query at the end, clamped >=0).
// QPT=16: one LDS broadcast read feeds 16 fma-chains -> VALU-bound.
// grid = (B * natmax, SPLIT, 2) = 1024 blocks -> 4 blocks/CU, 4 waves/SIMD.
// Each (dir,b,split) block writes its mins to a private minsplit row:
// no atomics, bit-deterministic.
// ---------------------------------------------------------------------------
__global__ void __launch_bounds__(TPB) nn_kernel(
    const float* __restrict__ pred,
    const float* __restrict__ target,
    const int*   __restrict__ label,
    float* __restrict__ minsplit,     // [2][B][SPLIT][stride]
    int B, int N, int M, int natmax, int stride)
{
    __shared__ float4 tile[TPB];

    const int dir = blockIdx.z;
    const float* __restrict__ A  = dir ? target : pred;
    const float* __restrict__ Bp = dir ? pred   : target;
    const int NA = dir ? M : N;
    const int NB = dir ? N : M;
    const int* __restrict__ labB = dir ? label : nullptr;

    const int natiles = (NA + TPB * QPT - 1) / (TPB * QPT);
    const int b  = blockIdx.x / natmax;
    const int at = blockIdx.x - b * natmax;
    if (at >= natiles) return;

    const size_t abase = (size_t)b * NA;

    float px[QPT], py[QPT], pz[QPT], pn[QPT], best[QPT];
#pragma unroll
    for (int q = 0; q < QPT; ++q) {
        int a = at * (TPB * QPT) + q * TPB + threadIdx.x;
        int idx = (a < NA) ? a : 0;
        const float* sp = A + (abase + idx) * 3;
        px[q] = sp[0];
        py[q] = sp[1];
        pz[q] = sp[2];
        pn[q] = fmaf(px[q], px[q], fmaf(py[q], py[q], pz[q] * pz[q]));
        best[q] = 3.0e38f;
    }

    const int slen = (NB + SPLIT - 1) / SPLIT;
    const int sbeg = blockIdx.y * slen;
    const int send = min(sbeg + slen, NB);
    const size_t bbase = (size_t)b * NB;

    for (int c = sbeg; c < send; c += TPB) {
        const int cnt = min(send - c, TPB);
        if (threadIdx.x < cnt) {
            int m = c + threadIdx.x;
            const float* sp = Bp + (bbase + m) * 3;
            float x = sp[0], y = sp[1], z = sp[2];
            float tn = fmaf(x, x, fmaf(y, y, z * z));
            if (labB != nullptr && labB[bbase + m] != 1) {   // invalid point
                x = 0.0f; y = 0.0f; z = 0.0f; tn = 1.0e10f;
            }
            tile[threadIdx.x] = make_float4(-2.f * x, -2.f * y, -2.f * z, tn);
        }
        __syncthreads();

        const int jeven = cnt & ~1;
#pragma unroll 2
        for (int j = 0; j < jeven; j += 2) {
            float4 t0 = tile[j];      // wave-uniform -> LDS broadcast
            float4 t1 = tile[j + 1];
#pragma unroll
            for (int q = 0; q < QPT; ++q) {
                float v0 = fmaf(px[q], t0.x, fmaf(py[q], t0.y, fmaf(pz[q], t0.z, t0.w)));
                float v1 = fmaf(px[q], t1.x, fmaf(py[q], t1.y, fmaf(pz[q], t1.z, t1.w)));
                best[q] = fminf(best[q], fminf(v0, v1));   // -> v_min3_f32
            }
        }
        if (cnt & 1) {
            float4 t0 = tile[cnt - 1];
#pragma unroll
            for (int q = 0; q < QPT; ++q) {
                float v0 = fmaf(px[q], t0.x, fmaf(py[q], t0.y, fmaf(pz[q], t0.z, t0.w)));
                best[q] = fminf(best[q], v0);
            }
        }
        __syncthreads();              // protect tile before next stage write
    }

    float* out = minsplit + (((size_t)dir * B + b) * SPLIT + blockIdx.y) * stride;
#pragma unroll
    for (int q = 0; q < QPT; ++q) {
        int a = at * (TPB * QPT) + q * TPB + threadIdx.x;
        if (a < NA) {
            out[a] = fmaxf(best[q] + pn[q], 0.0f);
        }
    }
}

// ---------------------------------------------------------------------------
// reduce1: one block per (dir, b, 64-query chunk). 256 threads = 64 queries
// x 4 slice-groups; each thread min-reduces 32 slices with fully coalesced
// loads (lanes 0..63 read 64 consecutive floats per slice). LDS combine of
// the 4 groups, then sqrt + masked sum, wave-level shuffle reduce -> one
// partial (sum, count) per block. No atomics, fixed order, deterministic.
// ---------------------------------------------------------------------------
__global__ void __launch_bounds__(RTPB) reduce1_kernel(
    const float* __restrict__ minsplit,
    const int* __restrict__ label,
    float* __restrict__ pS, float* __restrict__ pC,
    int B, int N, int M, int chunksN, int chunksM, int stride)
{
    __shared__ float red[RTPB];
    const int r = blockIdx.x;

    int dir, b, ch, NA;
    if (r < B * chunksN) { dir = 0; b = r / chunksN; ch = r - b * chunksN; NA = N; }
    else { int r2 = r - B * chunksN; dir = 1; b = r2 / chunksM; ch = r2 - b * chunksM; NA = M; }

    const int lane = threadIdx.x & 63;
    const int sg   = threadIdx.x >> 6;           // slice group 0..3
    const int q    = ch * QCHUNK + lane;

    const float* base = minsplit + ((size_t)(dir * B + b) * SPLIT) * stride + q;

    float m = 3.0e38f;
    if (q < NA) {
#pragma unroll 8
        for (int sp = sg; sp < SPLIT; sp += 4) {
            m = fminf(m, base[(size_t)sp * stride]);
        }
    }
    red[threadIdx.x] = m;
    __syncthreads();

    if (threadIdx.x < QCHUNK) {
        float mm = fminf(fminf(red[lane], red[64 + lane]),
                         fminf(red[128 + lane], red[192 + lane]));
        float s = 0.0f, cc = 0.0f;
        if (q < NA) {
            if (dir == 0) {
                if (label[(size_t)b * N + q] == 1) { s = sqrtf(mm); cc = 1.0f; }
            } else {
                s = sqrtf(mm);
            }
        }
        // wave-level fixed-order reduce over 64 lanes
        for (int off = 32; off > 0; off >>= 1) {
            s  += __shfl_down(s, off);
            cc += __shfl_down(cc, off);
        }
        if (lane == 0) { pS[r] = s; pC[r] = cc; }
    }
}

// ---------------------------------------------------------------------------
// final: single tiny block. Wave w handles (dir,b) pair p = w, w+4, ...;
// lane-strided sums over that pair's chunks + shuffle tree (fixed order).
// Plain loads are coherent across the dispatch boundary. Deterministic.
// ---------------------------------------------------------------------------
#define MAXB 64
__global__ void __launch_bounds__(256) final_kernel(
    const float* __restrict__ pS, const float* __restrict__ pC,
    float* __restrict__ out, int B, int M, int chunksN, int chunksM)
{
    __shared__ float S[2 * MAXB], C[2 * MAXB];
    const int wave = threadIdx.x >> 6;
    const int lane = threadIdx.x & 63;

    for (int p = wave; p < 2 * B; p += 4) {
        const int dir = (p >= B);
        const int b   = dir ? (p - B) : p;
        const int nch = dir ? chunksM : chunksN;
        const int off = dir ? (B * chunksN + b * chunksM) : (b * chunksN);
        float s = 0.0f, cc = 0.0f;
        for (int i = lane; i < nch; i += 64) {
            s  += pS[off + i];
            cc += pC[off + i];
        }
        for (int o = 32; o > 0; o >>= 1) {
            s  += __shfl_down(s, o);
            cc += __shfl_down(cc, o);
        }
        if (lane == 0) { S[p] = s; C[p] = cc; }
    }
    __syncthreads();

    if (threadIdx.x == 0) {
        float acc = 0.0f;
        for (int b = 0; b < B; ++b) {
            float m1 = S[b] / fmaxf(C[b], 1.0f);
            float m2 = S[B + b] / (float)M;
            acc += 0.5f * (m1 + m2);
        }
        out[0] = acc / (float)B;   // * LOSS_WEIGHT (== 1.0)
    }
}

// ---------------------------------------------------------------------------
extern "C" void kernel_launch(void* const* d_in, const int* in_sizes, int n_in,
                              void* d_out, int out_size, void* d_ws, size_t ws_size,
                              hipStream_t stream) {
    const float* pred   = (const float*)d_in[0];  // B*N*3 f32
    const float* target = (const float*)d_in[1];  // B*M*3 f32
    const int*   label  = (const int*)  d_in[2];  // B*N   i32

    const int B = in_sizes[3];                 // nums has shape (B,)
    const int N = in_sizes[2] / B;             // label is B*N
    const int M = in_sizes[1] / (3 * B);       // target is B*M*3

    const int stride = (N > M) ? N : M;

    // workspace layout (~16.8 MiB of the provided scratch)
    float* minsplit = (float*)d_ws;                               // 2*B*SPLIT*stride
    const int chunksN = (N + QCHUNK - 1) / QCHUNK;
    const int chunksM = (M + QCHUNK - 1) / QCHUNK;
    const int nred = B * (chunksN + chunksM);
    float* pS = minsplit + (size_t)2 * B * SPLIT * stride;        // nred
    float* pC = pS + nred;                                        // nred

    const int nat1 = (N + TPB * QPT - 1) / (TPB * QPT);
    const int nat2 = (M + TPB * QPT - 1) / (TPB * QPT);
    const int natmax = (nat1 > nat2) ? nat1 : nat2;
    dim3 g(B * natmax, SPLIT, 2);
    nn_kernel<<<g, TPB, 0, stream>>>(pred, target, label, minsplit,
                                     B, N, M, natmax, stride);

    reduce1_kernel<<<nred, RTPB, 0, stream>>>(minsplit, label, pS, pC,
                                              B, N, M, chunksN, chunksM, stride);

    final_kernel<<<1, 256, 0, stream>>>(pS, pC, (float*)d_out,
                                        B, M, chunksN, chunksM);
}